// Round 6
// baseline (155.307 us; speedup 1.0000x reference)
//
#include <hip/hip_runtime.h>
#include <stdint.h>

#define M_TOTAL 32768   // B*T
#define NUMS    512
#define DIM     1024
#define TOPK    33

typedef __bf16 bf16_t;
typedef bf16_t bf16x8 __attribute__((ext_vector_type(8)));
typedef float  f32x4  __attribute__((ext_vector_type(4)));
typedef unsigned short ushort_t;

__device__ __forceinline__ ushort_t f2bf(float f) {
    union { float f; uint32_t u; } x; x.f = f;
    uint32_t r = x.u + 0x7FFFu + ((x.u >> 16) & 1u);
    return (ushort_t)(r >> 16);
}
__device__ __forceinline__ float bf2f(uint32_t u) {
    union { uint32_t u; float f; } x; x.u = u << 16;
    return x.f;
}

// global_load_lds: wave-uniform LDS base (HW adds lane*16), per-lane global src
#define GLDS16(g, l) __builtin_amdgcn_global_load_lds( \
    (const __attribute__((address_space(1))) void*)(g), \
    (__attribute__((address_space(3))) void*)(l), 16, 0, 0)

// ---------------------------------------------------------------------------
// prep: mem fp32 [512][1024] -> memB bf16 [512][1024] and memT bf16 [1024][512]
// ---------------------------------------------------------------------------
__global__ void prep_kernel(const float* __restrict__ mem,
                            ushort_t* __restrict__ memB,
                            ushort_t* __restrict__ memT) {
    __shared__ float tile[32][33];
    const int bi = blockIdx.x;      // 0..15
    const int bj = blockIdx.y;      // 0..31
    const int t  = threadIdx.x;     // 256
    const int r  = t >> 3;
    const int c4 = (t & 7) * 4;

    const float4 v = *(const float4*)(mem + (size_t)(bi * 32 + r) * DIM + bj * 32 + c4);
    ushort4 b;
    b.x = f2bf(v.x); b.y = f2bf(v.y); b.z = f2bf(v.z); b.w = f2bf(v.w);
    *(ushort4*)(memB + (size_t)(bi * 32 + r) * DIM + bj * 32 + c4) = b;
    tile[r][c4 + 0] = v.x; tile[r][c4 + 1] = v.y;
    tile[r][c4 + 2] = v.z; tile[r][c4 + 3] = v.w;
    __syncthreads();
    ushort4 o;
    o.x = f2bf(tile[c4 + 0][r]); o.y = f2bf(tile[c4 + 1][r]);
    o.z = f2bf(tile[c4 + 2][r]); o.w = f2bf(tile[c4 + 3][r]);
    *(ushort4*)(memT + (size_t)(bj * 32 + r) * NUMS + bi * 32 + c4) = o;
}

// ---------------------------------------------------------------------------
// G1: tile 64x512, BK=64, 16 K-steps, FULL double-buffer (A 8KBx2, B 64KBx2 =
// 144KB LDS, 1 block/CU). 8 waves (2x4), wave tile 32x128, acc[2][8].
// All staging issued at step TOP: B(t+1) via GLDS (1-step lead), A(t+2) fp32
// to regs (2-step lead). One vmcnt(0)+lgkm(0)+barrier per step — every load
// it waits on is >= 1 full step old, so the drain is stall-free.
// 128B rows, 8-slot swizzle: LDS slot s of row r holds global chunk s^(r&7).
// ---------------------------------------------------------------------------
__global__ __launch_bounds__(512, 2)
void g1_kernel(const float* __restrict__ data,
               const ushort_t* __restrict__ memB,
               ushort_t* __restrict__ att,
               float* __restrict__ temporal) {
    __shared__ __align__(16) unsigned char smem[147456];
    // layout: A0@0(8K) A1@8192 B0@16384(64K) B1@81920(64K)
    const int t    = threadIdx.x;
    const int lane = t & 63;
    const int wid  = t >> 6;        // 0..7
    const int wr   = wid >> 2;      // 0..1 : 32 rows
    const int wc   = wid & 3;       // 0..3 : 128 cols
    const int kq   = lane >> 4;     // 0..3
    const int m0   = blockIdx.x * 64;

    f32x4 zero = {0.f, 0.f, 0.f, 0.f};
    f32x4 acc[2][8];
#pragma unroll
    for (int m = 0; m < 2; ++m)
#pragma unroll
        for (int n = 0; n < 8; ++n) acc[m][n] = zero;

    // A staging: thread -> row ar=t>>3 (0..63), dest slot t&7, src chunk (t&7)^(ar&7)
    const int ar  = t >> 3;
    const int asl = t & 7;
    const float* aSrc = data + (size_t)(m0 + ar) * DIM + (asl ^ (ar & 7)) * 8;
    const int aWOff = ar * 128 + asl * 16;            // + bufA*8192

    // B staging: wave wid stages rows wid*64..+63; 8 GLDS x 8 rows
    const ushort_t* bSrc = memB + (size_t)(wid * 64 + (lane >> 3)) * DIM
                         + ((lane & 7) ^ (lane >> 3)) * 8;
    const int bDstW = 16384 + wid * 8192;             // + bufB*65536 + i*1024

    // fragment read bases (slot xor: ^ 64 flips chunk bit2)
    const int arow = wr * 32 + (lane & 15);
    const int aR   = arow * 128 + ((kq ^ (arow & 7)) << 4);          // + m*2048
    const int bcol = wc * 128 + (lane & 15);
    const int bR   = 16384 + bcol * 128 + ((kq ^ (bcol & 7)) << 4);  // + n*2048

    float4 pa0, pa1, qa0, qa1;

    // ---- prologue: A0->pa, A1->qa, GLDS B0; drain; cvt A0 -> bufA0
    pa0 = *(const float4*)(aSrc);
    pa1 = *(const float4*)(aSrc + 4);
    qa0 = *(const float4*)(aSrc + 64);
    qa1 = *(const float4*)(aSrc + 68);
#pragma unroll
    for (int i = 0; i < 8; ++i)
        GLDS16(bSrc + (size_t)i * 8 * DIM, smem + bDstW + i * 1024);
    asm volatile("s_waitcnt vmcnt(0)" ::: "memory");
    {
        bf16x8 cv;
        cv[0] = (bf16_t)pa0.x; cv[1] = (bf16_t)pa0.y; cv[2] = (bf16_t)pa0.z; cv[3] = (bf16_t)pa0.w;
        cv[4] = (bf16_t)pa1.x; cv[5] = (bf16_t)pa1.y; cv[6] = (bf16_t)pa1.z; cv[7] = (bf16_t)pa1.w;
        *(bf16x8*)(smem + aWOff) = cv;
    }

#define G1_STEP(T_, CV0, CV1, LD0, LD1, DO_LDA, DO_GB, DO_CVT)                  \
    {                                                                           \
        asm volatile("s_waitcnt vmcnt(0) lgkmcnt(0)" ::: "memory");             \
        __builtin_amdgcn_s_barrier();                                           \
        asm volatile("" ::: "memory");                                          \
        const int bcur = (T_) & 1;                                              \
        if (DO_LDA) {                                                           \
            const float* as = aSrc + ((T_) + 2) * 64;                           \
            LD0 = *(const float4*)(as);                                         \
            LD1 = *(const float4*)(as + 4);                                     \
        }                                                                       \
        if (DO_GB) {                                                            \
            const ushort_t* bs = bSrc + ((T_) + 1) * 64;                        \
            unsigned char* bd = smem + bDstW + ((((T_) + 1) & 1) ? 65536 : 0);  \
            _Pragma("unroll") for (int i = 0; i < 8; ++i)                       \
                GLDS16(bs + (size_t)i * 8 * DIM, bd + i * 1024);                \
        }                                                                       \
        const int ab = bcur ? 8192 : 0;                                         \
        const int bb = bcur ? 65536 : 0;                                        \
        bf16x8 fa[2], fb[8], ga[2], gb[8];                                      \
        _Pragma("unroll") for (int m = 0; m < 2; ++m) {                         \
            fa[m] = *(const bf16x8*)(smem + ab + (aR + m * 2048));              \
            ga[m] = *(const bf16x8*)(smem + ab + ((aR + m * 2048) ^ 64));       \
        }                                                                       \
        _Pragma("unroll") for (int n = 0; n < 8; ++n) {                         \
            fb[n] = *(const bf16x8*)(smem + bb + (bR + n * 2048));              \
            gb[n] = *(const bf16x8*)(smem + bb + ((bR + n * 2048) ^ 64));       \
        }                                                                       \
        __builtin_amdgcn_s_setprio(1);                                          \
        _Pragma("unroll") for (int m = 0; m < 2; ++m)                           \
            _Pragma("unroll") for (int n = 0; n < 8; ++n)                       \
                acc[m][n] = __builtin_amdgcn_mfma_f32_16x16x32_bf16(            \
                    fa[m], fb[n], acc[m][n], 0, 0, 0);                          \
        __builtin_amdgcn_s_setprio(0);                                          \
        if (DO_CVT) {                                                           \
            bf16x8 cv;                                                          \
            cv[0] = (bf16_t)CV0.x; cv[1] = (bf16_t)CV0.y;                       \
            cv[2] = (bf16_t)CV0.z; cv[3] = (bf16_t)CV0.w;                       \
            cv[4] = (bf16_t)CV1.x; cv[5] = (bf16_t)CV1.y;                       \
            cv[6] = (bf16_t)CV1.z; cv[7] = (bf16_t)CV1.w;                       \
            *(bf16x8*)(smem + (bcur ? 0 : 8192) + aWOff) = cv;                  \
        }                                                                       \
        __builtin_amdgcn_s_setprio(1);                                          \
        _Pragma("unroll") for (int m = 0; m < 2; ++m)                           \
            _Pragma("unroll") for (int n = 0; n < 8; ++n)                       \
                acc[m][n] = __builtin_amdgcn_mfma_f32_16x16x32_bf16(            \
                    ga[m], gb[n], acc[m][n], 0, 0, 0);                          \
        __builtin_amdgcn_s_setprio(0);                                          \
    }

    // even t: cvt qa (A(t+1)), load pa (A(t+2)); odd t: cvt pa, load qa
    for (int tb = 0; tb < 7; ++tb) {
        G1_STEP(2 * tb,     qa0, qa1, pa0, pa1, 1, 1, 1)
        G1_STEP(2 * tb + 1, pa0, pa1, qa0, qa1, 1, 1, 1)
    }
    G1_STEP(14, qa0, qa1, pa0, pa1, 0, 1, 1)   // cvt A15, stage B15, no A-load
    G1_STEP(15, pa0, pa1, qa0, qa1, 0, 0, 0)   // compute only
#undef G1_STEP

    // ---- epilogue: att tile 64x512 bf16 over Bbuf0 (disjoint from buf1 used at t=15)
    ushort_t* lAtt = (ushort_t*)(smem + 16384);
#pragma unroll
    for (int m = 0; m < 2; ++m)
#pragma unroll
        for (int n = 0; n < 8; ++n)
#pragma unroll
            for (int reg = 0; reg < 4; ++reg) {
                const int row = wr * 32 + m * 16 + (lane >> 4) * 4 + reg;
                const int col = wc * 128 + n * 16 + (lane & 15);
                const float x = acc[m][n][reg] * 0.03125f;   // /sqrt(1024)
                const float s = 1.0f / (1.0f + __expf(-x));
                lAtt[row * 512 + col] = f2bf(s);
            }
    __syncthreads();
    // att -> global (coalesced): 64x512 bf16 = 4096 uint4, 512 thr x 8 iters
    {
        uint4* gdst = (uint4*)(att + (size_t)m0 * 512);
        const uint4* lsrc = (const uint4*)lAtt;
#pragma unroll
        for (int i = 0; i < 8; ++i) {
            const int idx = i * 512 + t;
            gdst[idx] = lsrc[idx];
        }
    }
    // top-33 mean via ballot radix-select; 8 rows per wave; bit15 always 0
    for (int ri = 0; ri < 8; ++ri) {
        const int row = wid * 8 + ri;
        const uint4 rv = *(const uint4*)(lAtt + row * 512 + lane * 8);
        uint32_t u[8];
        u[0] = rv.x & 0xFFFFu; u[1] = rv.x >> 16;
        u[2] = rv.y & 0xFFFFu; u[3] = rv.y >> 16;
        u[4] = rv.z & 0xFFFFu; u[5] = rv.z >> 16;
        u[6] = rv.w & 0xFFFFu; u[7] = rv.w >> 16;
        uint32_t tc = 0;
#pragma unroll
        for (int b = 14; b >= 0; --b) {
            const uint32_t cand = tc | (1u << b);
            int c = 0;
#pragma unroll
            for (int j = 0; j < 8; ++j)
                c += __popcll(__ballot(u[j] >= cand));
            if (c >= TOPK) tc = cand;
        }
        float sgt = 0.f; int cgt = 0;
#pragma unroll
        for (int j = 0; j < 8; ++j) {
            if (u[j] > tc) { sgt += bf2f(u[j]); cgt++; }
        }
#pragma unroll
        for (int off = 32; off >= 1; off >>= 1) {
            sgt += __shfl_xor(sgt, off);
            cgt += __shfl_xor(cgt, off);
        }
        if (lane == 0)
            temporal[m0 + row] = (sgt + (float)(TOPK - cgt) * bf2f(tc)) * (1.0f / 33.0f);
    }
}

// ---------------------------------------------------------------------------
// G2: aug = att bf16 @ memT^T. 128x128, BK=64, 4 waves, double-buffered,
// XCD-swizzled. (unchanged — ~30us)
// ---------------------------------------------------------------------------
__global__ __launch_bounds__(256, 2)
void g2_kernel(const ushort_t* __restrict__ att,
               const ushort_t* __restrict__ memT,
               float* __restrict__ aug) {
    __shared__ __align__(16) unsigned char smem[65536];
    const int t    = threadIdx.x;
    const int lane = t & 63;
    const int wid  = t >> 6;
    const int wr   = wid >> 1;
    const int wc   = wid & 1;
    const int wg = (blockIdx.x & 7) * 256 + (blockIdx.x >> 3);
    const int m0 = (wg >> 3) * 128;
    const int n0 = (wg & 7) * 128;

    f32x4 zero = {0.f, 0.f, 0.f, 0.f};
    f32x4 acc[4][4];
#pragma unroll
    for (int m = 0; m < 4; ++m)
#pragma unroll
        for (int n = 0; n < 4; ++n) acc[m][n] = zero;

    const int srcoff = (((lane & 7) ^ (lane >> 3)) & 7) * 8;
    const ushort_t* aS = att  + (size_t)(m0 + wid * 32 + (lane >> 3)) * 512 + srcoff;
    const ushort_t* bS = memT + (size_t)(n0 + wid * 32 + (lane >> 3)) * 512 + srcoff;

#define G2_STAGE(K0_, PAR_)                                                     \
    {                                                                           \
        unsigned char* da = smem + ((PAR_) ? 16384 : 0) + wid * 4096 + lane * 16; \
        unsigned char* db = da + 32768;                                         \
        const ushort_t* sa = aS + (K0_);                                        \
        const ushort_t* sb = bS + (K0_);                                        \
        GLDS16(sa,            da);        GLDS16(sb,            db);            \
        GLDS16(sa +  8 * 512, da + 1024); GLDS16(sb +  8 * 512, db + 1024);     \
        GLDS16(sa + 16 * 512, da + 2048); GLDS16(sb + 16 * 512, db + 2048);     \
        GLDS16(sa + 24 * 512, da + 3072); GLDS16(sb + 24 * 512, db + 3072);     \
    }

    G2_STAGE(0, 0)
    __syncthreads();

    for (int tt = 0; tt < 8; ++tt) {
        if (tt < 7) {
            if ((tt & 1) == 0) G2_STAGE((tt + 1) * 64, 1)
            else               G2_STAGE((tt + 1) * 64, 0)
        }
        const unsigned char* ab = smem + ((tt & 1) ? 16384 : 0);
        const unsigned char* bb = ab + 32768;
#pragma unroll
        for (int ki = 0; ki < 2; ++ki) {
            const int ch = ki * 4 + (lane >> 4);
            bf16x8 af[4], bfr[4];
#pragma unroll
            for (int m = 0; m < 4; ++m) {
                const int row = wr * 64 + m * 16 + (lane & 15);
                af[m] = *(const bf16x8*)(ab + row * 128 + ((ch ^ (row & 7)) << 4));
            }
#pragma unroll
            for (int n = 0; n < 4; ++n) {
                const int col = wc * 64 + n * 16 + (lane & 15);
                bfr[n] = *(const bf16x8*)(bb + col * 128 + ((ch ^ (col & 7)) << 4));
            }
#pragma unroll
            for (int m = 0; m < 4; ++m)
#pragma unroll
                for (int n = 0; n < 4; ++n)
                    acc[m][n] = __builtin_amdgcn_mfma_f32_16x16x32_bf16(
                        af[m], bfr[n], acc[m][n], 0, 0, 0);
        }
        __syncthreads();
    }
#undef G2_STAGE

#pragma unroll
    for (int m = 0; m < 4; ++m)
#pragma unroll
        for (int n = 0; n < 4; ++n)
#pragma unroll
            for (int reg = 0; reg < 4; ++reg) {
                const int row = m0 + wr * 64 + m * 16 + (lane >> 4) * 4 + reg;
                const int col = n0 + wc * 64 + n * 16 + (lane & 15);
                aug[(size_t)row * DIM + col] = acc[m][n][reg];
            }
}

// ---------------------------------------------------------------------------
extern "C" void kernel_launch(void* const* d_in, const int* in_sizes, int n_in,
                              void* d_out, int out_size, void* d_ws, size_t ws_size,
                              hipStream_t stream) {
    const float* data = (const float*)d_in[0];   // [16,2048,1024]
    const float* mem  = (const float*)d_in[1];   // [512,1024]
    float* temporal = (float*)d_out;             // [32768]
    float* aug      = (float*)d_out + M_TOTAL;   // [32768,1024]

    ushort_t* memB = (ushort_t*)d_ws;                    // 512*1024 bf16 (1MB)
    ushort_t* memT = memB + (size_t)NUMS * DIM;          // 1024*512 bf16 (1MB)
    ushort_t* attw = memT + (size_t)DIM * NUMS;          // 32768*512 bf16 (32MB)

    prep_kernel<<<dim3(16, 32), 256, 0, stream>>>(mem, memB, memT);
    g1_kernel<<<M_TOTAL / 64, 512, 0, stream>>>(data, memB, attw, temporal);
    g2_kernel<<<(M_TOTAL / 128) * (DIM / 128), 256, 0, stream>>>(attw, memT, aug);
}